// Round 1
// baseline (218.305 us; speedup 1.0000x reference)
//
#include <hip/hip_runtime.h>

typedef float f32x4 __attribute__((ext_vector_type(4)));
typedef short bf16x8 __attribute__((ext_vector_type(8)));

// ---- workspace layout (bytes) ----
// B1s: [16 kb][544 cols][128 B]  (bf16, chunk-swizzled)   = 1,114,112
// W2s: [1024 cols][640 B]        (bf16, chunk-swizzled)   =   655,360
// ACT: [32768 rows][640 B]       (bf16, chunk-swizzled)   = 20,971,520
#define B1S_KBSZ 69632
#define W2S_OFF  1114112
#define ACT_OFF  1769472
// total ws required: 22,740,992 bytes (~21.7 MB)

__device__ __forceinline__ unsigned short f2bf(float f) {
  unsigned int u = __float_as_uint(f);
  return (unsigned short)((u + 0x7FFFu + ((u >> 16) & 1u)) >> 16);
}
__device__ __forceinline__ float bf2f(unsigned short s) {
  return __uint_as_float(((unsigned int)s) << 16);
}
__device__ __forceinline__ unsigned int pack2(float a, float b) {
  return (unsigned int)f2bf(a) | ((unsigned int)f2bf(b) << 16);
}
__device__ __forceinline__ void async16(const void* g, void* l) {
  __builtin_amdgcn_global_load_lds(
      (const __attribute__((address_space(1))) unsigned int*)g,
      (__attribute__((address_space(3))) unsigned int*)l, 16, 0, 0);
}

// ---------------- prep: pack [W1|Wr] -> B1s (bf16, [kb][col][swizzled 128B]) ----------------
__global__ __launch_bounds__(256) void prep_b1(const float* __restrict__ W1,
                                               const float* __restrict__ Wr,
                                               unsigned char* __restrict__ B1s) {
  int t = blockIdx.x * 256 + threadIdx.x;
  if (t >= 544 * 16) return;
  int col = t % 544;
  int kb  = t / 544;
  unsigned char* dst = B1s + kb * B1S_KBSZ + col * 128;
  int key = col & 7;
  int e   = col >> 6;
  int hh  = col & 63;
  #pragma unroll
  for (int c = 0; c < 8; ++c) {
    float v[8];
    #pragma unroll
    for (int jj = 0; jj < 8; ++jj) {
      int k = kb * 64 + c * 8 + jj;
      float f;
      if (col < 512)      f = W1[(e * 1024 + k) * 64 + hh];   // W1[e][k][hh]
      else if (col < 520) f = Wr[k * 8 + (col - 512)];        // Wr[k][e]
      else                f = 0.0f;
      v[jj] = f;
    }
    *(uint4*)(dst + ((c ^ key) * 16)) =
        make_uint4(pack2(v[0], v[1]), pack2(v[2], v[3]), pack2(v[4], v[5]), pack2(v[6], v[7]));
  }
}

// ---------------- prep: pack [W2 ; b2 ; 0] -> W2s (bf16, [col][swizzled 640B]) ----------------
__global__ __launch_bounds__(256) void prep_w2(const float* __restrict__ W2,
                                               const float* __restrict__ b2,
                                               unsigned char* __restrict__ W2s) {
  int c = blockIdx.x * 256 + threadIdx.x;
  if (c >= 1024) return;
  unsigned char* dst = W2s + c * 640;
  int key = c & 7;
  #pragma unroll 1
  for (int cj = 0; cj < 40; ++cj) {
    float v[8];
    #pragma unroll
    for (int jj = 0; jj < 8; ++jj) {
      int k = cj * 8 + jj;
      float f;
      if (k < 256)      f = W2[k * 1024 + c];          // W2[e][h][c], k=e*32+h
      else if (k < 264) f = b2[(k - 256) * 1024 + c];  // b2[e][c]
      else              f = 0.0f;
      v[jj] = f;
    }
    int dstc = (cj & ~7) | ((cj & 7) ^ key);
    *(uint4*)(dst + dstc * 16) =
        make_uint4(pack2(v[0], v[1]), pack2(v[2], v[3]), pack2(v[4], v[5]), pack2(v[6], v[7]));
  }
}

// ---------------- kernel 1: X @ [W1|Wr], softmax, SwiGLU, scale-by-p -> ACT ----------------
__global__ __launch_bounds__(512) void moe_gemm1(
    const float* __restrict__ x, const float* __restrict__ br, const float* __restrict__ b1,
    const unsigned char* __restrict__ B1s, unsigned char* __restrict__ ACT) {
  __shared__ __align__(16) unsigned char smem[77824];  // B: [0,69632) X: [69632,77824); epilogue: h_lds
  __shared__ float logit_lds[64][8];
  unsigned short* h_lds = (unsigned short*)smem;       // [64][560] bf16 (row stride 560 to dodge banks)

  const int tid  = threadIdx.x;
  const int lane = tid & 63;
  const int w    = tid >> 6;   // 8 waves
  const int mf   = w & 3;      // m-fragment (16 rows)
  const int nh   = w >> 2;     // n-half (17 frags each)
  const int m0   = blockIdx.x * 64;

  f32x4 acc[17];
  #pragma unroll
  for (int i = 0; i < 17; ++i) acc[i] = f32x4{0.f, 0.f, 0.f, 0.f};

  const int srow = tid >> 3;
  const int sc8  = tid & 7;
  const int xchunk = ((sc8 ^ (srow & 7)) * 16);
  const float* xsrc_base = x + (size_t)(m0 + srow) * 1024 + sc8 * 8;

  const int f15  = lane & 15;
  const int fhi  = lane >> 4;
  const int fkey = lane & 7;

  #pragma unroll 1
  for (int ks = 0; ks < 16; ++ks) {
    __syncthreads();
    {  // stage B-tile: 68 KiB linear (swizzle pre-baked in ws)
      const unsigned char* bsrc = B1s + ks * B1S_KBSZ + lane * 16;
      for (int i = w; i < 68; i += 8) async16(bsrc + i * 1024, smem + i * 1024);
    }
    {  // stage X-tile: f32 -> bf16 -> swizzled LDS
      const float* s = xsrc_base + ks * 64;
      f32x4 a = *(const f32x4*)s;
      f32x4 b = *(const f32x4*)(s + 4);
      *(uint4*)(smem + 69632 + srow * 128 + xchunk) =
          make_uint4(pack2(a.x, a.y), pack2(a.z, a.w), pack2(b.x, b.y), pack2(b.z, b.w));
    }
    __syncthreads();
    #pragma unroll
    for (int ksub = 0; ksub < 2; ++ksub) {
      int chnk = ((ksub * 4 + fhi) ^ fkey) * 16;
      bf16x8 af = *(const bf16x8*)(smem + 69632 + (mf * 16 + f15) * 128 + chnk);
      #pragma unroll
      for (int nf = 0; nf < 17; ++nf) {
        int col = (nh * 17 + nf) * 16 + f15;
        bf16x8 bfr = *(const bf16x8*)(smem + col * 128 + chnk);
        acc[nf] = __builtin_amdgcn_mfma_f32_16x16x32_bf16(af, bfr, acc[nf], 0, 0, 0);
      }
    }
  }

  __syncthreads();  // all LDS reads done; safe to alias smem as h_lds
  if (nh == 1 && f15 < 8) {  // frag 32 holds router logits (cols 512..519) — keep f32
    #pragma unroll
    for (int r = 0; r < 4; ++r) logit_lds[mf * 16 + fhi * 4 + r][f15] = acc[15][r];
  }
  #pragma unroll
  for (int nf = 0; nf < 17; ++nf) {
    int col = (nh * 17 + nf) * 16 + f15;
    #pragma unroll
    for (int r = 0; r < 4; ++r)
      h_lds[(mf * 16 + fhi * 4 + r) * 560 + col] = f2bf(acc[nf][r]);
  }
  __syncthreads();

  {  // epilogue: thread = (row, expert)
    const int row = tid >> 3;
    const int e   = tid & 7;
    const unsigned short* hrow = h_lds + row * 560;
    float lg[8];
    #pragma unroll
    for (int j = 0; j < 8; ++j) lg[j] = logit_lds[row][j] + br[j];
    float mx = lg[0];
    #pragma unroll
    for (int j = 1; j < 8; ++j) mx = fmaxf(mx, lg[j]);
    float ssum = 0.f;
    #pragma unroll
    for (int j = 0; j < 8; ++j) ssum += __expf(lg[j] - mx);
    float pe = __expf(lg[e] - mx) / ssum;

    unsigned char* actrow = ACT + (size_t)(m0 + row) * 640;
    int key = row & 7;
    #pragma unroll
    for (int cc = 0; cc < 4; ++cc) {
      float av[8];
      #pragma unroll
      for (int jj = 0; jj < 8; ++jj) {
        int h = cc * 8 + jj;
        float xp = bf2f(hrow[e * 64 + h]) + b1[e * 64 + h];
        float g  = bf2f(hrow[e * 64 + 32 + h]) + b1[e * 64 + 32 + h];
        float sg = 1.f / (1.f + __expf(-g));
        av[jj] = xp * g * sg * pe;  // p_e * xp * silu(gate)
      }
      int cj = e * 4 + cc;
      int dstc = (cj & ~7) | ((cj & 7) ^ key);
      *(uint4*)(actrow + dstc * 16) = make_uint4(pack2(av[0], av[1]), pack2(av[2], av[3]),
                                                 pack2(av[4], av[5]), pack2(av[6], av[7]));
    }
    *(unsigned short*)(actrow + 512 + key * 16 + e * 2) = f2bf(pe);  // append p (bias rows)
    if (e < 7) {
      int j = e + 1;
      *(uint4*)(actrow + 512 + ((j ^ key) * 16)) = make_uint4(0, 0, 0, 0);  // zero pad K 264..319
    }
  }
}

// ---------------- kernel 2: ACT[32768,320] @ W2s[320,1024] -> out (f32) ----------------
__global__ __launch_bounds__(256) void moe_gemm2(
    const unsigned char* __restrict__ ACT, const unsigned char* __restrict__ W2s,
    float* __restrict__ out) {
  __shared__ __align__(16) unsigned char smem[24576];  // A: 8 KB, B: 16 KB
  const int tid  = threadIdx.x;
  const int lane = tid & 63;
  const int w    = tid >> 6;   // 4 waves, one m-fragment each
  const int m0   = (blockIdx.x >> 3) * 64;
  const int n0   = (blockIdx.x & 7) * 128;

  const int f15  = lane & 15;
  const int fhi  = lane >> 4;
  const int fkey = lane & 7;
  const int glrow = lane >> 3;
  const int glc   = lane & 7;

  f32x4 acc[8];
  #pragma unroll
  for (int i = 0; i < 8; ++i) acc[i] = f32x4{0.f, 0.f, 0.f, 0.f};

  #pragma unroll 1
  for (int kb = 0; kb < 5; ++kb) {
    __syncthreads();
    for (int i = w; i < 8; i += 4)
      async16(ACT + (size_t)(m0 + i * 8 + glrow) * 640 + kb * 128 + glc * 16, smem + i * 1024);
    for (int i = w; i < 16; i += 4)
      async16(W2s + (size_t)(n0 + i * 8 + glrow) * 640 + kb * 128 + glc * 16,
              smem + 8192 + i * 1024);
    __syncthreads();
    #pragma unroll
    for (int ksub = 0; ksub < 2; ++ksub) {
      int chnk = ((ksub * 4 + fhi) ^ fkey) * 16;
      bf16x8 af = *(const bf16x8*)(smem + (w * 16 + f15) * 128 + chnk);
      #pragma unroll
      for (int nf = 0; nf < 8; ++nf) {
        bf16x8 bfr = *(const bf16x8*)(smem + 8192 + (nf * 16 + f15) * 128 + chnk);
        acc[nf] = __builtin_amdgcn_mfma_f32_16x16x32_bf16(af, bfr, acc[nf], 0, 0, 0);
      }
    }
  }
  float* ob = out + (size_t)(m0 + w * 16 + fhi * 4) * 1024 + n0 + f15;
  #pragma unroll
  for (int nf = 0; nf < 8; ++nf) {
    #pragma unroll
    for (int r = 0; r < 4; ++r) ob[(size_t)r * 1024 + nf * 16] = acc[nf][r];
  }
}

extern "C" void kernel_launch(void* const* d_in, const int* in_sizes, int n_in,
                              void* d_out, int out_size, void* d_ws, size_t ws_size,
                              hipStream_t stream) {
  const float* x  = (const float*)d_in[0];
  const float* Wr = (const float*)d_in[1];
  const float* br = (const float*)d_in[2];
  const float* W1 = (const float*)d_in[3];
  const float* b1 = (const float*)d_in[4];
  const float* W2 = (const float*)d_in[5];
  const float* b2 = (const float*)d_in[6];
  float* out = (float*)d_out;
  unsigned char* ws  = (unsigned char*)d_ws;
  unsigned char* B1s = ws;
  unsigned char* W2s = ws + W2S_OFF;
  unsigned char* ACT = ws + ACT_OFF;

  hipLaunchKernelGGL(prep_b1, dim3(34), dim3(256), 0, stream, W1, Wr, B1s);
  hipLaunchKernelGGL(prep_w2, dim3(4), dim3(256), 0, stream, W2, b2, W2s);
  hipLaunchKernelGGL(moe_gemm1, dim3(512), dim3(512), 0, stream, x, br, b1, B1s, ACT);
  hipLaunchKernelGGL(moe_gemm2, dim3(4096), dim3(256), 0, stream, ACT, W2s, out);
}

// Round 2
// 195.380 us; speedup vs baseline: 1.1173x; 1.1173x over previous
//
#include <hip/hip_runtime.h>

typedef float f32x4 __attribute__((ext_vector_type(4)));
typedef short bf16x8 __attribute__((ext_vector_type(8)));

// ---- workspace layout (bytes) ----
// B1s: [16 kb][528 cols][128 B]  (bf16, chunk-swizzled; cols 512-519 router, 520-527 zero)
// W2s: [1024 cols][640 B]        (bf16, chunk-swizzled; rows 256-263 = b2, 264-319 zero)
// ACT: [32768 rows][640 B]       (bf16, chunk-swizzled; k 256-263 = p, 264-319 zero)
#define B1S_KBSZ 67584
#define W2S_OFF  1081344
#define ACT_OFF  1736704
// total ws required: 22,708,224 bytes

__device__ __forceinline__ unsigned short f2bf(float f) {
  unsigned int u = __float_as_uint(f);
  return (unsigned short)((u + 0x7FFFu + ((u >> 16) & 1u)) >> 16);
}
__device__ __forceinline__ unsigned int pack2(float a, float b) {
  return (unsigned int)f2bf(a) | ((unsigned int)f2bf(b) << 16);
}
__device__ __forceinline__ unsigned int cvtpk(float a, float b) {
  unsigned int r;
  asm("v_cvt_pk_bf16_f32 %0, %1, %2" : "=v"(r) : "v"(a), "v"(b));
  return r;
}
__device__ __forceinline__ void async16(const void* g, void* l) {
  __builtin_amdgcn_global_load_lds(
      (const __attribute__((address_space(1))) unsigned int*)g,
      (__attribute__((address_space(3))) unsigned int*)l, 16, 0, 0);
}

// ---------------- prep: pack [W1|Wr|0] -> B1s ----------------
__global__ __launch_bounds__(256) void prep_b1(const float* __restrict__ W1,
                                               const float* __restrict__ Wr,
                                               unsigned char* __restrict__ B1s) {
  int t = blockIdx.x * 256 + threadIdx.x;
  if (t >= 528 * 16) return;
  int col = t % 528;
  int kb  = t / 528;
  unsigned char* dst = B1s + kb * B1S_KBSZ + col * 128;
  int key = col & 7;
  int e   = col >> 6;
  int hh  = col & 63;
  #pragma unroll
  for (int c = 0; c < 8; ++c) {
    float v[8];
    #pragma unroll
    for (int jj = 0; jj < 8; ++jj) {
      int k = kb * 64 + c * 8 + jj;
      float f;
      if (col < 512)      f = W1[(e * 1024 + k) * 64 + hh];   // W1[e][k][hh]
      else if (col < 520) f = Wr[k * 8 + (col - 512)];        // Wr[k][e]
      else                f = 0.0f;
      v[jj] = f;
    }
    *(uint4*)(dst + ((c ^ key) * 16)) =
        make_uint4(pack2(v[0], v[1]), pack2(v[2], v[3]), pack2(v[4], v[5]), pack2(v[6], v[7]));
  }
}

// ---------------- prep: pack [W2 ; b2 ; 0] -> W2s ----------------
__global__ __launch_bounds__(256) void prep_w2(const float* __restrict__ W2,
                                               const float* __restrict__ b2,
                                               unsigned char* __restrict__ W2s) {
  int c = blockIdx.x * 256 + threadIdx.x;
  if (c >= 1024) return;
  unsigned char* dst = W2s + c * 640;
  int key = c & 7;
  #pragma unroll 1
  for (int cj = 0; cj < 40; ++cj) {
    float v[8];
    #pragma unroll
    for (int jj = 0; jj < 8; ++jj) {
      int k = cj * 8 + jj;
      float f;
      if (k < 256)      f = W2[k * 1024 + c];          // W2[e][h][c], k=e*32+h
      else if (k < 264) f = b2[(k - 256) * 1024 + c];  // b2[e][c]
      else              f = 0.0f;
      v[jj] = f;
    }
    int dstc = (cj & ~7) | ((cj & 7) ^ key);
    *(uint4*)(dst + dstc * 16) =
        make_uint4(pack2(v[0], v[1]), pack2(v[2], v[3]), pack2(v[4], v[5]), pack2(v[6], v[7]));
  }
}

// ---------------- kernel 1: per expert-pair tile, fused router/softmax/SwiGLU ----------------
// grid 1024 = 256 M-tiles x 4 pairs; block 512 = 8 waves (4 m-groups x 2 n-groups)
__global__ __launch_bounds__(512, 4) void moe_gemm1(
    const float* __restrict__ x, const float* __restrict__ br, const float* __restrict__ b1,
    const unsigned char* __restrict__ B1s, unsigned char* __restrict__ ACT) {
  __shared__ __align__(16) unsigned char smem[34816];  // B [0,18432) + A [18432,34816)
  __shared__ float logit_lds[128][8];

  const int tid  = threadIdx.x;
  const int lane = tid & 63;
  const int w    = tid >> 6;
  const int mg   = w >> 1;   // rows mg*32 .. +32
  const int ng   = w & 1;    // 0: expert-lo cols 0-63 + router; 1: expert-hi cols 64-127
  const int f15  = lane & 15;
  const int fhi  = lane >> 4;

  const int wid   = ((blockIdx.x & 7) << 7) + (blockIdx.x >> 3);  // XCD-chunked, 1024=8*128
  const int mtile = wid >> 2;
  const int p     = wid & 3;
  const int m0    = mtile << 7;

  f32x4 acc[2][5];
  #pragma unroll
  for (int a = 0; a < 2; ++a)
    #pragma unroll
    for (int b = 0; b < 5; ++b) acc[a][b] = f32x4{0.f, 0.f, 0.f, 0.f};

  const int srow = tid >> 2;
  const int scg  = tid & 3;
  const float* xrow = x + (size_t)(m0 + srow) * 1024 + scg * 16;
  unsigned char* awr0 = smem + 18432 + srow * 128 + (((scg * 2)     ^ (srow & 7)) * 16);
  unsigned char* awr1 = smem + 18432 + srow * 128 + (((scg * 2 + 1) ^ (srow & 7)) * 16);

  int bco[5];
  #pragma unroll
  for (int i = 0; i < 5; ++i) {
    int cf = ng ? (4 + i) : (i < 4 ? i : 8);
    bco[i] = (cf * 16 + f15) * 128;
  }
  const int NB = ng ? 4 : 5;

  f32x4 areg[4];
  { const f32x4* s = (const f32x4*)xrow; areg[0]=s[0]; areg[1]=s[1]; areg[2]=s[2]; areg[3]=s[3]; }

  #pragma unroll 1
  for (int ks = 0; ks < 16; ++ks) {
    __syncthreads();
    const unsigned char* bsrc = B1s + ks * B1S_KBSZ;
    for (int i = w; i < 18; i += 8) {
      int gc0 = (i < 16) ? (p * 128 + i * 8) : (512 + (i - 16) * 8);
      async16(bsrc + gc0 * 128 + lane * 16, smem + i * 1024 + lane * 16);
    }
    {
      uint4 u0, u1;
      u0.x = cvtpk(areg[0].x, areg[0].y); u0.y = cvtpk(areg[0].z, areg[0].w);
      u0.z = cvtpk(areg[1].x, areg[1].y); u0.w = cvtpk(areg[1].z, areg[1].w);
      u1.x = cvtpk(areg[2].x, areg[2].y); u1.y = cvtpk(areg[2].z, areg[2].w);
      u1.z = cvtpk(areg[3].x, areg[3].y); u1.w = cvtpk(areg[3].z, areg[3].w);
      *(uint4*)awr0 = u0; *(uint4*)awr1 = u1;
    }
    if (ks < 15) {
      const f32x4* s = (const f32x4*)(xrow + (ks + 1) * 64);
      areg[0]=s[0]; areg[1]=s[1]; areg[2]=s[2]; areg[3]=s[3];
    }
    __syncthreads();
    #pragma unroll
    for (int ksub = 0; ksub < 2; ++ksub) {
      const int ch = ((ksub * 4 + fhi) ^ (f15 & 7)) * 16;
      bf16x8 af0 = *(const bf16x8*)(smem + 18432 + (mg * 32      + f15) * 128 + ch);
      bf16x8 af1 = *(const bf16x8*)(smem + 18432 + (mg * 32 + 16 + f15) * 128 + ch);
      #pragma unroll
      for (int i = 0; i < 5; ++i) {
        if (i < NB) {
          bf16x8 bfr = *(const bf16x8*)(smem + bco[i] + ch);
          acc[0][i] = __builtin_amdgcn_mfma_f32_16x16x32_bf16(af0, bfr, acc[0][i], 0, 0, 0);
          acc[1][i] = __builtin_amdgcn_mfma_f32_16x16x32_bf16(af1, bfr, acc[1][i], 0, 0, 0);
        }
      }
    }
  }

  __syncthreads();
  if (ng == 0 && f15 < 8) {  // router logits (frag idx 4 = cols 512-519), add br
    float brv = br[f15];
    #pragma unroll
    for (int mf = 0; mf < 2; ++mf)
      #pragma unroll
      for (int r = 0; r < 4; ++r)
        logit_lds[mg * 32 + mf * 16 + fhi * 4 + r][f15] = acc[mf][4][r] + brv;
  }
  __syncthreads();

  const int e = p * 2 + ng;
  const float b1x0 = b1[e * 64 + f15],      b1x1 = b1[e * 64 + 16 + f15];
  const float b1g0 = b1[e * 64 + 32 + f15], b1g1 = b1[e * 64 + 48 + f15];
  unsigned short* hb = (unsigned short*)smem;              // [128][72] (144 B stride)
  unsigned short* pb = (unsigned short*)(smem + 18432);    // [128][8]

  #pragma unroll
  for (int mf = 0; mf < 2; ++mf) {
    #pragma unroll
    for (int r = 0; r < 4; ++r) {
      int row = mg * 32 + mf * 16 + fhi * 4 + r;
      float lg0 = logit_lds[row][0], lg1 = logit_lds[row][1];
      float lg2 = logit_lds[row][2], lg3 = logit_lds[row][3];
      float lg4 = logit_lds[row][4], lg5 = logit_lds[row][5];
      float lg6 = logit_lds[row][6], lg7 = logit_lds[row][7];
      float mx = fmaxf(fmaxf(fmaxf(lg0, lg1), fmaxf(lg2, lg3)),
                       fmaxf(fmaxf(lg4, lg5), fmaxf(lg6, lg7)));
      float ssum = __expf(lg0 - mx) + __expf(lg1 - mx) + __expf(lg2 - mx) + __expf(lg3 - mx) +
                   __expf(lg4 - mx) + __expf(lg5 - mx) + __expf(lg6 - mx) + __expf(lg7 - mx);
      float rinv = 1.f / ssum;
      float pe = __expf(logit_lds[row][e] - mx) * rinv;
      #pragma unroll
      for (int ci = 0; ci < 2; ++ci) {
        float xv = acc[mf][ci][r]     + (ci ? b1x1 : b1x0);
        float gv = acc[mf][ci + 2][r] + (ci ? b1g1 : b1g0);
        float av = pe * xv * gv / (1.f + __expf(-gv));   // pe * xp * silu(gate)
        hb[row * 72 + ng * 32 + ci * 16 + f15] = f2bf(av);
      }
      if (ng == 0 && f15 < 8) {
        float pr = __expf(logit_lds[row][f15] - mx) * rinv;
        pb[row * 8 + f15] = f2bf(pr);
      }
    }
  }
  __syncthreads();

  {
    const int row = tid >> 2, q = tid & 3, key = row & 7;
    unsigned char* arow = ACT + (size_t)(m0 + row) * 640;
    #pragma unroll
    for (int j = 0; j < 2; ++j) {
      int c = q * 2 + j;
      uint4 v = *(const uint4*)(smem + row * 144 + c * 16);
      *(uint4*)(arow + p * 128 + ((c ^ key) * 16)) = v;
    }
    if (p == 0) {  // p-append (k 256-263) + zero pad (k 264-319)
      #pragma unroll
      for (int j = 0; j < 2; ++j) {
        int c = q * 2 + j;
        uint4 v = make_uint4(0, 0, 0, 0);
        if (c == 0) v = *(const uint4*)(smem + 18432 + row * 16);
        *(uint4*)(arow + 512 + ((c ^ key) * 16)) = v;
      }
    }
  }
}

// ---------------- kernel 2: ACT[32768,320] @ W2s[320,1024] -> out (f32) ----------------
// grid 2048 = 256 m x 8 n; block 256 = 4 waves (2x2), wave tile 64x64
__global__ __launch_bounds__(256, 4) void moe_gemm2(
    const unsigned char* __restrict__ ACT, const unsigned char* __restrict__ W2s,
    float* __restrict__ out) {
  __shared__ __align__(16) unsigned char smem[32768];  // A [0,16384) B [16384,32768)
  const int tid  = threadIdx.x;
  const int lane = tid & 63;
  const int w    = tid >> 6;
  const int wm   = w >> 1, wn = w & 1;
  const int f15  = lane & 15, fhi = lane >> 4;
  const int r8   = lane >> 3, c8 = lane & 7;

  const int wid = ((blockIdx.x & 7) << 8) + (blockIdx.x >> 3);  // 2048 = 8*256
  const int m0  = (wid >> 3) * 128;
  const int n0  = (wid & 7) * 128;

  f32x4 acc[4][4];
  #pragma unroll
  for (int a = 0; a < 4; ++a)
    #pragma unroll
    for (int b = 0; b < 4; ++b) acc[a][b] = f32x4{0.f, 0.f, 0.f, 0.f};

  #pragma unroll 1
  for (int kb = 0; kb < 5; ++kb) {
    __syncthreads();
    for (int i = w; i < 16; i += 4)
      async16(ACT + (size_t)(m0 + i * 8 + r8) * 640 + kb * 128 + c8 * 16,
              smem + i * 1024 + lane * 16);
    for (int i = w; i < 16; i += 4)
      async16(W2s + (size_t)(n0 + i * 8 + r8) * 640 + kb * 128 + c8 * 16,
              smem + 16384 + i * 1024 + lane * 16);
    __syncthreads();
    #pragma unroll
    for (int ksub = 0; ksub < 2; ++ksub) {
      const int ch = ((ksub * 4 + fhi) ^ (f15 & 7)) * 16;
      bf16x8 af[4];
      #pragma unroll
      for (int mf = 0; mf < 4; ++mf)
        af[mf] = *(const bf16x8*)(smem + (wm * 64 + mf * 16 + f15) * 128 + ch);
      #pragma unroll
      for (int nf = 0; nf < 4; ++nf) {
        bf16x8 bfr = *(const bf16x8*)(smem + 16384 + (wn * 64 + nf * 16 + f15) * 128 + ch);
        #pragma unroll
        for (int mf = 0; mf < 4; ++mf)
          acc[mf][nf] = __builtin_amdgcn_mfma_f32_16x16x32_bf16(af[mf], bfr, acc[mf][nf], 0, 0, 0);
      }
    }
  }
  float* ob = out + (size_t)(m0 + wm * 64 + fhi * 4) * 1024 + n0 + wn * 64 + f15;
  #pragma unroll
  for (int mf = 0; mf < 4; ++mf)
    #pragma unroll
    for (int nf = 0; nf < 4; ++nf)
      #pragma unroll
      for (int r = 0; r < 4; ++r)
        ob[(size_t)(mf * 16 + r) * 1024 + nf * 16] = acc[mf][nf][r];
}

extern "C" void kernel_launch(void* const* d_in, const int* in_sizes, int n_in,
                              void* d_out, int out_size, void* d_ws, size_t ws_size,
                              hipStream_t stream) {
  const float* x  = (const float*)d_in[0];
  const float* Wr = (const float*)d_in[1];
  const float* br = (const float*)d_in[2];
  const float* W1 = (const float*)d_in[3];
  const float* b1 = (const float*)d_in[4];
  const float* W2 = (const float*)d_in[5];
  const float* b2 = (const float*)d_in[6];
  float* out = (float*)d_out;
  unsigned char* ws  = (unsigned char*)d_ws;
  unsigned char* B1s = ws;
  unsigned char* W2s = ws + W2S_OFF;
  unsigned char* ACT = ws + ACT_OFF;

  hipLaunchKernelGGL(prep_b1, dim3(33), dim3(256), 0, stream, W1, Wr, B1s);
  hipLaunchKernelGGL(prep_w2, dim3(4), dim3(256), 0, stream, W2, b2, W2s);
  hipLaunchKernelGGL(moe_gemm1, dim3(1024), dim3(512), 0, stream, x, br, b1, B1s, ACT);
  hipLaunchKernelGGL(moe_gemm2, dim3(2048), dim3(256), 0, stream, ACT, W2s, out);
}